// Round 1
// baseline (7816.695 us; speedup 1.0000x reference)
//
#include <hip/hip_runtime.h>

#define NXY 160
#define NT 12
#define HID 64
#define SP (NXY*NXY)          // 25600
#define OCC 16                // output channels per thread
#define HPLANE (HID*SP)       // one r or i plane of hidden state: 1,638,400 floats

__device__ __forceinline__ int refl(int p) {
    return p < 0 ? -p : (p >= NXY ? 2*(NXY-1) - p : p);
}

// -------------------- precompute: pre = cconv(input,w_i2h) + cconv(iter,w_ih) + biases ----------
__global__ __launch_bounds__(256)
void precompute_kernel(const float* __restrict__ in_r,  const float* __restrict__ in_i,
                       const float* __restrict__ it_r,  const float* __restrict__ it_i,
                       const float* __restrict__ w2_r,  const float* __restrict__ w2_i,
                       const float* __restrict__ b2_r,  const float* __restrict__ b2_i,
                       const float* __restrict__ wh_r,  const float* __restrict__ wh_i,
                       const float* __restrict__ bh_r,  const float* __restrict__ bh_i,
                       float2* __restrict__ pre)
{
    const int t    = blockIdx.z;
    const int oc0  = blockIdx.y * OCC;
    const int tile = blockIdx.x;
    const int tid  = threadIdx.x;
    const int x = (tile / 10) * 16 + (tid >> 4);
    const int y = (tile % 10) * 16 + (tid & 15);

    int offs[9];
    #pragma unroll
    for (int dx = -1; dx <= 1; ++dx)
        #pragma unroll
        for (int dy = -1; dy <= 1; ++dy)
            offs[(dx+1)*3 + (dy+1)] = refl(x+dx)*NXY + refl(y+dy);

    float accr[OCC], acci[OCC];
    #pragma unroll
    for (int o = 0; o < OCC; ++o) {
        accr[o] = b2_r[oc0+o] + bh_r[oc0+o];
        acci[o] = b2_i[oc0+o] + bh_i[oc0+o];
    }

    // 2 channels from input with w_i2h
    for (int ic = 0; ic < 2; ++ic) {
        const float* pr = in_r + (ic*NT + t)*SP;
        const float* pi = in_i + (ic*NT + t)*SP;
        float xr[9], xi[9];
        #pragma unroll
        for (int k = 0; k < 9; ++k) { xr[k] = pr[offs[k]]; xi[k] = pi[offs[k]]; }
        #pragma unroll
        for (int o = 0; o < OCC; ++o) {
            const float* wr = w2_r + ((oc0+o)*2 + ic)*9;
            const float* wi = w2_i + ((oc0+o)*2 + ic)*9;
            #pragma unroll
            for (int k = 0; k < 9; ++k) {
                accr[o] = fmaf(xr[k],  wr[k], accr[o]);
                accr[o] = fmaf(-xi[k], wi[k], accr[o]);
                acci[o] = fmaf(xr[k],  wi[k], acci[o]);
                acci[o] = fmaf(xi[k],  wr[k], acci[o]);
            }
        }
    }
    // 64 channels from iter with w_ih
    for (int ic = 0; ic < HID; ++ic) {
        const float* pr = it_r + (ic*NT + t)*SP;
        const float* pi = it_i + (ic*NT + t)*SP;
        float xr[9], xi[9];
        #pragma unroll
        for (int k = 0; k < 9; ++k) { xr[k] = pr[offs[k]]; xi[k] = pi[offs[k]]; }
        #pragma unroll
        for (int o = 0; o < OCC; ++o) {
            const float* wr = wh_r + ((oc0+o)*HID + ic)*9;
            const float* wi = wh_i + ((oc0+o)*HID + ic)*9;
            #pragma unroll
            for (int k = 0; k < 9; ++k) {
                accr[o] = fmaf(xr[k],  wr[k], accr[o]);
                accr[o] = fmaf(-xi[k], wi[k], accr[o]);
                acci[o] = fmaf(xr[k],  wi[k], acci[o]);
                acci[o] = fmaf(xi[k],  wr[k], acci[o]);
            }
        }
    }
    const int xy = x*NXY + y;
    #pragma unroll
    for (int o = 0; o < OCC; ++o)
        pre[(t*HID + oc0 + o)*SP + xy] = make_float2(accr[o], acci[o]);
}

// -------------------- one recurrence step, both directions (gridDim.z = 2) ----------------------
// launch s: fwd consumes pre[s] -> writes out[t=s]; bwd consumes pre[11-s] -> writes out[t=11-s].
// For s<=5 both directions are the FIRST writer of their t; for s>=6 both accumulate.
__global__ __launch_bounds__(256)
void step_kernel(float* __restrict__ hws,              // 4 h buffers: [dir][parity][2 planes][HPLANE]
                 const float2* __restrict__ pre,
                 const float* __restrict__ w_r, const float* __restrict__ w_i,
                 const float* __restrict__ b_r, const float* __restrict__ b_i,
                 const float* __restrict__ mod_b,
                 float2* __restrict__ out,
                 int s)
{
    const int dir  = blockIdx.z;
    const int t    = dir == 0 ? s : (NT-1 - s);
    const int oc0  = blockIdx.y * OCC;
    const int tile = blockIdx.x;
    const int tid  = threadIdx.x;
    const int x = (tile / 10) * 16 + (tid >> 4);
    const int y = (tile % 10) * 16 + (tid & 15);
    const int xy = x*NXY + y;

    const int first = (s <= 5);
    const int has_h = (s > 0);

    float* hdir = hws + (size_t)dir * 2 * 2 * HPLANE;
    const float* h_in  = hdir + (size_t)(s & 1) * 2 * HPLANE;
    float*       h_out = hdir + (size_t)((s+1) & 1) * 2 * HPLANE;

    int offs[9];
    #pragma unroll
    for (int dx = -1; dx <= 1; ++dx)
        #pragma unroll
        for (int dy = -1; dy <= 1; ++dy)
            offs[(dx+1)*3 + (dy+1)] = refl(x+dx)*NXY + refl(y+dy);

    float accr[OCC], acci[OCC];
    #pragma unroll
    for (int o = 0; o < OCC; ++o) {
        float2 p = pre[(t*HID + oc0 + o)*SP + xy];
        accr[o] = p.x + b_r[oc0+o];
        acci[o] = p.y + b_i[oc0+o];
    }

    if (has_h) {
        for (int ic = 0; ic < HID; ++ic) {
            const float* pr = h_in + ic*SP;
            const float* pi = h_in + HPLANE + ic*SP;
            float xr[9], xi[9];
            #pragma unroll
            for (int k = 0; k < 9; ++k) { xr[k] = pr[offs[k]]; xi[k] = pi[offs[k]]; }
            #pragma unroll
            for (int o = 0; o < OCC; ++o) {
                const float* wr = w_r + ((oc0+o)*HID + ic)*9;
                const float* wi = w_i + ((oc0+o)*HID + ic)*9;
                #pragma unroll
                for (int k = 0; k < 9; ++k) {
                    accr[o] = fmaf(xr[k],  wr[k], accr[o]);
                    accr[o] = fmaf(-xi[k], wi[k], accr[o]);
                    acci[o] = fmaf(xr[k],  wi[k], acci[o]);
                    acci[o] = fmaf(xi[k],  wr[k], acci[o]);
                }
            }
        }
    }

    #pragma unroll
    for (int o = 0; o < OCC; ++o) {
        const float zr = accr[o], zi = acci[o];
        const float mag = sqrtf(zr*zr + zi*zi);
        const float sc  = fmaxf(mag + mod_b[oc0+o], 0.0f) / (mag + 1e-8f);
        const float hr = sc*zr, hi = sc*zi;
        h_out[(oc0+o)*SP + xy]          = hr;
        h_out[HPLANE + (oc0+o)*SP + xy] = hi;
        const int oidx = ((oc0+o)*NT + t)*SP + xy;
        if (first) {
            out[oidx] = make_float2(hr, hi);
        } else {
            float2 old = out[oidx];
            out[oidx] = make_float2(old.x + hr, old.y + hi);
        }
    }
}

extern "C" void kernel_launch(void* const* d_in, const int* in_sizes, int n_in,
                              void* d_out, int out_size, void* d_ws, size_t ws_size,
                              hipStream_t stream)
{
    const float* in_r  = (const float*)d_in[0];
    const float* in_i  = (const float*)d_in[1];
    const float* it_r  = (const float*)d_in[2];
    const float* it_i  = (const float*)d_in[3];
    const float* w2_r  = (const float*)d_in[4];
    const float* w2_i  = (const float*)d_in[5];
    const float* b2_r  = (const float*)d_in[6];
    const float* b2_i  = (const float*)d_in[7];
    const float* whh_r = (const float*)d_in[8];
    const float* whh_i = (const float*)d_in[9];
    const float* bhh_r = (const float*)d_in[10];
    const float* bhh_i = (const float*)d_in[11];
    const float* wih_r = (const float*)d_in[12];
    const float* wih_i = (const float*)d_in[13];
    const float* bih_r = (const float*)d_in[14];
    const float* bih_i = (const float*)d_in[15];
    const float* mod_b = (const float*)d_in[16];

    float*  ws   = (float*)d_ws;
    float2* pre  = (float2*)ws;                       // NT*HID*SP float2 = 39,321,600 floats
    float*  hws  = ws + (size_t)2 * NT * HID * SP;    // 4 * 2*HPLANE floats
    float2* out  = (float2*)d_out;

    precompute_kernel<<<dim3(100, HID/OCC, NT), 256, 0, stream>>>(
        in_r, in_i, it_r, it_i, w2_r, w2_i, b2_r, b2_i, wih_r, wih_i, bih_r, bih_i, pre);

    for (int s = 0; s < NT; ++s) {
        step_kernel<<<dim3(100, HID/OCC, 2), 256, 0, stream>>>(
            hws, pre, whh_r, whh_i, bhh_r, bhh_i, mod_b, out, s);
    }
}

// Round 2
// 3834.565 us; speedup vs baseline: 2.0385x; 2.0385x over previous
//
#include <hip/hip_runtime.h>

#define NXY 160
#define NT 12
#define HID 64
#define SP (NXY*NXY)          // 25600
#define OCC 8                 // output channels per thread
#define H2 (HID*SP)           // one hidden buffer in float2 units

__device__ __forceinline__ int refl(int p) {
    return p < 0 ? -p : (p >= NXY ? 2*(NXY-1) - p : p);
}

// Each thread: 2 horizontally-adjacent pixels (x, y0) (x, y0+1), 8 output channels.
// Block = 256 threads = 16x rows x 16 y-pairs -> tile 16x x 32y. 10*5 = 50 tiles.

// -------------------- precompute: pre = cconv(input,w_i2h) + cconv(iter,w_ih) + biases ----------
__global__ __launch_bounds__(256, 4)
void precompute_kernel(const float* __restrict__ in_r,  const float* __restrict__ in_i,
                       const float* __restrict__ it_r,  const float* __restrict__ it_i,
                       const float* __restrict__ w2_r,  const float* __restrict__ w2_i,
                       const float* __restrict__ b2_r,  const float* __restrict__ b2_i,
                       const float* __restrict__ wh_r,  const float* __restrict__ wh_i,
                       const float* __restrict__ bh_r,  const float* __restrict__ bh_i,
                       float4* __restrict__ pre4)
{
    const int t    = blockIdx.z;
    const int oc0  = blockIdx.y * OCC;
    const int tile = blockIdx.x;
    const int tid  = threadIdx.x;
    const int x  = (tile / 5) * 16 + (tid >> 4);
    const int y0 = (tile % 5) * 32 + (tid & 15) * 2;

    // 3 rows x 4 cols window element offsets
    int offs[12];
    #pragma unroll
    for (int r = 0; r < 3; ++r)
        #pragma unroll
        for (int c = 0; c < 4; ++c)
            offs[r*4 + c] = refl(x-1+r)*NXY + refl(y0-1+c);

    float accr[OCC][2], acci[OCC][2];
    #pragma unroll
    for (int o = 0; o < OCC; ++o) {
        const float brv = b2_r[oc0+o] + bh_r[oc0+o];
        const float biv = b2_i[oc0+o] + bh_i[oc0+o];
        accr[o][0] = brv; accr[o][1] = brv;
        acci[o][0] = biv; acci[o][1] = biv;
    }

    // 2 channels from input with w_i2h
    for (int ic = 0; ic < 2; ++ic) {
        const float* pr = in_r + (ic*NT + t)*SP;
        const float* pi = in_i + (ic*NT + t)*SP;
        float xr[12], xi[12];
        #pragma unroll
        for (int k = 0; k < 12; ++k) { xr[k] = pr[offs[k]]; xi[k] = pi[offs[k]]; }
        #pragma unroll
        for (int o = 0; o < OCC; ++o) {
            const float* wrp = w2_r + ((oc0+o)*2 + ic)*9;
            const float* wip = w2_i + ((oc0+o)*2 + ic)*9;
            #pragma unroll
            for (int kk = 0; kk < 9; ++kk) {
                const float wr = wrp[kk], wi = wip[kk];
                const int wpos = (kk/3)*4 + (kk%3);
                #pragma unroll
                for (int p = 0; p < 2; ++p) {
                    accr[o][p] = fmaf(xr[wpos+p],  wr, accr[o][p]);
                    accr[o][p] = fmaf(-xi[wpos+p], wi, accr[o][p]);
                    acci[o][p] = fmaf(xr[wpos+p],  wi, acci[o][p]);
                    acci[o][p] = fmaf(xi[wpos+p],  wr, acci[o][p]);
                }
            }
        }
    }
    // 64 channels from iter with w_ih
    for (int ic = 0; ic < HID; ++ic) {
        const float* pr = it_r + (ic*NT + t)*SP;
        const float* pi = it_i + (ic*NT + t)*SP;
        float xr[12], xi[12];
        #pragma unroll
        for (int k = 0; k < 12; ++k) { xr[k] = pr[offs[k]]; xi[k] = pi[offs[k]]; }
        #pragma unroll
        for (int o = 0; o < OCC; ++o) {
            const float* wrp = wh_r + ((oc0+o)*HID + ic)*9;
            const float* wip = wh_i + ((oc0+o)*HID + ic)*9;
            #pragma unroll
            for (int kk = 0; kk < 9; ++kk) {
                const float wr = wrp[kk], wi = wip[kk];
                const int wpos = (kk/3)*4 + (kk%3);
                #pragma unroll
                for (int p = 0; p < 2; ++p) {
                    accr[o][p] = fmaf(xr[wpos+p],  wr, accr[o][p]);
                    accr[o][p] = fmaf(-xi[wpos+p], wi, accr[o][p]);
                    acci[o][p] = fmaf(xr[wpos+p],  wi, acci[o][p]);
                    acci[o][p] = fmaf(xi[wpos+p],  wr, acci[o][p]);
                }
            }
        }
    }
    const int xy = x*NXY + y0;   // even
    #pragma unroll
    for (int o = 0; o < OCC; ++o)
        pre4[(((t*HID + oc0 + o)*SP + xy) >> 1)] =
            make_float4(accr[o][0], acci[o][0], accr[o][1], acci[o][1]);
}

// -------------------- one recurrence step, both directions (gridDim.z = 2) ----------------------
// launch s: fwd consumes pre[s] -> writes out[t=s]; bwd consumes pre[11-s] -> writes out[t=11-s].
// For s<=5 both directions are the FIRST writer of their t; for s>=6 both accumulate.
__global__ __launch_bounds__(256, 4)
void step_kernel(float2* __restrict__ hws,             // 4 interleaved h buffers [dir][parity][H2]
                 const float4* __restrict__ pre4,
                 const float* __restrict__ w_r, const float* __restrict__ w_i,
                 const float* __restrict__ b_r, const float* __restrict__ b_i,
                 const float* __restrict__ mod_b,
                 float4* __restrict__ out4,
                 int s)
{
    const int dir  = blockIdx.z;
    const int t    = dir == 0 ? s : (NT-1 - s);
    const int oc0  = blockIdx.y * OCC;
    const int tile = blockIdx.x;
    const int tid  = threadIdx.x;
    const int x  = (tile / 5) * 16 + (tid >> 4);
    const int y0 = (tile % 5) * 32 + (tid & 15) * 2;
    const int xy = x*NXY + y0;   // even

    const int first = (s <= 5);
    const int has_h = (s > 0);

    float2* hdir = hws + (size_t)dir * 2 * H2;
    const float2* h_in  = hdir + (size_t)(s & 1) * H2;
    float2*       h_out = hdir + (size_t)((s+1) & 1) * H2;

    int offs[12];
    #pragma unroll
    for (int r = 0; r < 3; ++r)
        #pragma unroll
        for (int c = 0; c < 4; ++c)
            offs[r*4 + c] = refl(x-1+r)*NXY + refl(y0-1+c);

    float accr[OCC][2], acci[OCC][2];
    #pragma unroll
    for (int o = 0; o < OCC; ++o) {
        float4 p = pre4[(((t*HID + oc0 + o)*SP + xy) >> 1)];
        const float brv = b_r[oc0+o], biv = b_i[oc0+o];
        accr[o][0] = p.x + brv; acci[o][0] = p.y + biv;
        accr[o][1] = p.z + brv; acci[o][1] = p.w + biv;
    }

    if (has_h) {
        for (int ic = 0; ic < HID; ++ic) {
            const float2* hb = h_in + ic*SP;
            float xr[12], xi[12];
            #pragma unroll
            for (int k = 0; k < 12; ++k) {
                float2 v = hb[offs[k]];
                xr[k] = v.x; xi[k] = v.y;
            }
            #pragma unroll
            for (int o = 0; o < OCC; ++o) {
                const float* wrp = w_r + ((oc0+o)*HID + ic)*9;
                const float* wip = w_i + ((oc0+o)*HID + ic)*9;
                #pragma unroll
                for (int kk = 0; kk < 9; ++kk) {
                    const float wr = wrp[kk], wi = wip[kk];
                    const int wpos = (kk/3)*4 + (kk%3);
                    #pragma unroll
                    for (int p = 0; p < 2; ++p) {
                        accr[o][p] = fmaf(xr[wpos+p],  wr, accr[o][p]);
                        accr[o][p] = fmaf(-xi[wpos+p], wi, accr[o][p]);
                        acci[o][p] = fmaf(xr[wpos+p],  wi, acci[o][p]);
                        acci[o][p] = fmaf(xi[wpos+p],  wr, acci[o][p]);
                    }
                }
            }
        }
    }

    #pragma unroll
    for (int o = 0; o < OCC; ++o) {
        const float mb = mod_b[oc0+o];
        float hr[2], hi[2];
        #pragma unroll
        for (int p = 0; p < 2; ++p) {
            const float zr = accr[o][p], zi = acci[o][p];
            const float mag = sqrtf(zr*zr + zi*zi);
            const float sc  = fmaxf(mag + mb, 0.0f) / (mag + 1e-8f);
            hr[p] = sc*zr; hi[p] = sc*zi;
        }
        // hidden state (interleaved float2, consecutive pixels -> one float4 store)
        ((float4*)h_out)[(((oc0+o)*SP + xy) >> 1)] = make_float4(hr[0], hi[0], hr[1], hi[1]);
        const int oidx = (((oc0+o)*NT + t)*SP + xy) >> 1;
        if (first) {
            out4[oidx] = make_float4(hr[0], hi[0], hr[1], hi[1]);
        } else {
            float4 old = out4[oidx];
            out4[oidx] = make_float4(old.x + hr[0], old.y + hi[0],
                                     old.z + hr[1], old.w + hi[1]);
        }
    }
}

extern "C" void kernel_launch(void* const* d_in, const int* in_sizes, int n_in,
                              void* d_out, int out_size, void* d_ws, size_t ws_size,
                              hipStream_t stream)
{
    const float* in_r  = (const float*)d_in[0];
    const float* in_i  = (const float*)d_in[1];
    const float* it_r  = (const float*)d_in[2];
    const float* it_i  = (const float*)d_in[3];
    const float* w2_r  = (const float*)d_in[4];
    const float* w2_i  = (const float*)d_in[5];
    const float* b2_r  = (const float*)d_in[6];
    const float* b2_i  = (const float*)d_in[7];
    const float* whh_r = (const float*)d_in[8];
    const float* whh_i = (const float*)d_in[9];
    const float* bhh_r = (const float*)d_in[10];
    const float* bhh_i = (const float*)d_in[11];
    const float* wih_r = (const float*)d_in[12];
    const float* wih_i = (const float*)d_in[13];
    const float* bih_r = (const float*)d_in[14];
    const float* bih_i = (const float*)d_in[15];
    const float* mod_b = (const float*)d_in[16];

    float*  ws   = (float*)d_ws;
    float4* pre4 = (float4*)ws;                        // NT*HID*SP float2 = 157 MB
    float2* hws  = (float2*)(ws + (size_t)2 * NT * HID * SP);  // 4 * H2 float2 = 52 MB
    float4* out4 = (float4*)d_out;

    precompute_kernel<<<dim3(50, HID/OCC, NT), 256, 0, stream>>>(
        in_r, in_i, it_r, it_i, w2_r, w2_i, b2_r, b2_i, wih_r, wih_i, bih_r, bih_i, pre4);

    for (int s = 0; s < NT; ++s) {
        step_kernel<<<dim3(50, HID/OCC, 2), 256, 0, stream>>>(
            hws, pre4, whh_r, whh_i, bhh_r, bhh_i, mod_b, out4, s);
    }
}

// Round 3
// 1461.594 us; speedup vs baseline: 5.3481x; 2.6235x over previous
//
#include <hip/hip_runtime.h>

#define NXY 160
#define NT 12
#define SP 25600                 // 160*160
#define KC 36                    // K chunks of 32 (9 taps * 4 ic16-blocks)
#define SPH ((size_t)SP*128)     // ushorts per [hl] slab

typedef unsigned short u16;
typedef unsigned int u32;
typedef float f32x4 __attribute__((ext_vector_type(4)));
typedef __bf16 bf16x8 __attribute__((ext_vector_type(8)));

__device__ __forceinline__ int refl(int p){ return p<0 ? -p : (p>=NXY ? 2*(NXY-1)-p : p); }
__device__ __forceinline__ u16 bf16_rn(float x){
    u32 u = __float_as_uint(x);
    return (u16)((u + 0x7fffu + ((u>>16)&1u)) >> 16);
}
__device__ __forceinline__ float bf16_f(u16 h){ return __uint_as_float(((u32)h)<<16); }
__device__ __forceinline__ bf16x8 as_bf(uint4 v){ return __builtin_bit_cast(bf16x8, v); }

// ---------------- pack weights into A-fragment order: [hl][36][4 slot][128 m][8] ----------------
// k = c*32 + slot*8 + j ; c = tap*4 + icb ; ic = icb*16 + slot*4 + (j>>1) ; ri = j&1
// m<64 (real out): ri0 -> wr, ri1 -> -wi ; m>=64 (imag out): ri0 -> wi, ri1 -> wr
__global__ void pack_w_kernel(const float* __restrict__ wr, const float* __restrict__ wi,
                              u16* __restrict__ Ap)
{
    const int c = blockIdx.x, m = threadIdx.x;
    const int tap = c>>2, icb = c&3;
    const int oc = m & 63; const bool imr = m >= 64;
    for (int slot=0; slot<4; ++slot)
        for (int j=0; j<8; ++j){
            int ic = icb*16 + slot*4 + (j>>1);
            int ri = j&1;
            float vr = wr[(oc*64+ic)*9+tap], vi = wi[(oc*64+ic)*9+tap];
            float val = imr ? (ri ? vr : vi) : (ri ? -vi : vr);
            u16 h = bf16_rn(val);
            int idx = ((c*4+slot)*128+m)*8+j;
            Ap[idx] = h;
            Ap[KC*4*128*8 + idx] = bf16_rn(val - bf16_f(h));
        }
}

// ---------------- pack iter (2 time steps per launch) into pixel-major bf16 hi/lo ---------------
__global__ __launch_bounds__(256) void pack_iter_kernel(const float* __restrict__ it_r,
        const float* __restrict__ it_i, u16* __restrict__ H, int t0)
{
    __shared__ u32 smem[16384];
    const int t = t0 + blockIdx.y;
    u16* dst = H + (size_t)blockIdx.y * 2 * SPH;
    const int px0 = blockIdx.x * 128;
    const int tid = threadIdx.x;
    const int pxl = tid & 127, half = tid >> 7;
    const int px = px0 + pxl;
    for (int i=0; i<32; ++i){
        int ic = i*2 + half;
        float r  = it_r[((size_t)ic*NT + t)*SP + px];
        float im = it_i[((size_t)ic*NT + t)*SP + px];
        u16 rh = bf16_rn(r), ih = bf16_rn(im);
        u16 rl = bf16_rn(r - bf16_f(rh)), il = bf16_rn(im - bf16_f(ih));
        int dw = pxl*64 + (ic ^ (pxl&31));
        smem[dw]        = (u32)rh | ((u32)ih<<16);
        smem[8192 + dw] = (u32)rl | ((u32)il<<16);
    }
    __syncthreads();
    uint4* gh = (uint4*)dst;
    uint4* gl = (uint4*)(dst + SPH);
    for (int i=0; i<8; ++i){
        int pxr = i*16 + (tid>>4);
        int q = tid & 15;
        uint4 v, v2;
        #pragma unroll
        for (int d=0; d<4; ++d){
            ((u32*)&v )[d] = smem[        pxr*64 + ((q*4+d) ^ (pxr&31))];
            ((u32*)&v2)[d] = smem[8192 + pxr*64 + ((q*4+d) ^ (pxr&31))];
        }
        gh[(size_t)(px0+pxr)*16 + q] = v;
        gl[(size_t)(px0+pxr)*16 + q] = v2;
    }
}

// ---------------- i2h: 2-channel input conv + ALL biases -> pre (float2 [t][64][SP]) -------------
__global__ __launch_bounds__(256) void i2h_kernel(
    const float* __restrict__ in_r, const float* __restrict__ in_i,
    const float* __restrict__ w2r,  const float* __restrict__ w2i,
    const float* __restrict__ b2r,  const float* __restrict__ b2i,
    const float* __restrict__ bihr, const float* __restrict__ bihi,
    const float* __restrict__ bhhr, const float* __restrict__ bhhi,
    float2* __restrict__ pre)
{
    const int t = blockIdx.z, oc0 = blockIdx.y*8;
    const int px = blockIdx.x*256 + threadIdx.x;
    const int x = px/NXY, y = px - x*NXY;
    int offs[9];
    #pragma unroll
    for (int dx=-1; dx<=1; ++dx)
        #pragma unroll
        for (int dy=-1; dy<=1; ++dy)
            offs[(dx+1)*3+(dy+1)] = refl(x+dx)*NXY + refl(y+dy);
    float xr[2][9], xi[2][9];
    #pragma unroll
    for (int ic=0; ic<2; ++ic)
        #pragma unroll
        for (int k=0; k<9; ++k){
            xr[ic][k] = in_r[((size_t)ic*NT+t)*SP + offs[k]];
            xi[ic][k] = in_i[((size_t)ic*NT+t)*SP + offs[k]];
        }
    #pragma unroll
    for (int o=0; o<8; ++o){
        int oc = oc0+o;
        float ar = b2r[oc]+bihr[oc]+bhhr[oc];
        float ai = b2i[oc]+bihi[oc]+bhhi[oc];
        #pragma unroll
        for (int ic=0; ic<2; ++ic)
            #pragma unroll
            for (int k=0; k<9; ++k){
                float wr = w2r[(oc*2+ic)*9+k], wi = w2i[(oc*2+ic)*9+k];
                ar = fmaf(xr[ic][k], wr, ar); ar = fmaf(-xi[ic][k], wi, ar);
                ai = fmaf(xr[ic][k], wi, ai); ai = fmaf( xi[ic][k], wr, ai);
            }
        pre[((size_t)t*64+oc)*SP + px] = make_float2(ar, ai);
    }
}

// ---------------- the GEMM: MODE 0 = precompute (pre += W_ih * iter), MODE 1 = recurrence step --
template<int MODE>
__global__ __launch_bounds__(256, 2) void gemm_kernel(
    const u16* __restrict__ Apk,   // [2 hl][36][4][128][8]
    const u16* __restrict__ Bpit,  // MODE0: pit base (y-indexed); MODE1 unused
    float2* __restrict__ pre,      // MODE0: base for t0 (y adds); MODE1: full base
    float2* __restrict__ out,
    const float* __restrict__ modb,
    u16* __restrict__ H,
    int s)
{
    __shared__ u32 smem[16384];    // 64KB
    const int tid = threadIdx.x;
    const int lane = tid & 63, w = tid >> 6;
    const int l15 = lane & 15, l4 = lane >> 4;

    const u16* Bh; const u16* Bl; float2* pre_t;
    int dir = 0, t = 0;
    if constexpr (MODE==0){
        Bh = Bpit + (size_t)blockIdx.y*2*SPH; Bl = Bh + SPH;
        pre_t = pre + (size_t)blockIdx.y*64*SP;
    } else {
        dir = blockIdx.y;
        int rp = (s+1)&1;
        Bh = H + (size_t)(dir*2+rp)*2*SPH; Bl = Bh + SPH;
        t = dir ? (NT-1-s) : s;
        pre_t = pre + (size_t)t*64*SP;
    }

    const int px0 = blockIdx.x*128;
    const int wpx0 = px0 + w*32;

    int pxo[2][9];
    #pragma unroll
    for (int nt=0; nt<2; ++nt){
        int px = wpx0 + nt*16 + l15;
        int x = px/NXY, y = px - x*NXY;
        #pragma unroll
        for (int dx=-1; dx<=1; ++dx)
            #pragma unroll
            for (int dy=-1; dy<=1; ++dy)
                pxo[nt][(dx+1)*3+(dy+1)] = refl(x+dx)*NXY + refl(y+dy);
    }

    f32x4 acc[8][2];
    #pragma unroll
    for (int mt=0; mt<8; ++mt){ acc[mt][0] = 0.f; acc[mt][1] = 0.f; }

    const bool hasK = (MODE==0) || (s>0);
    if (hasK){
        const uint4* Ah4 = (const uint4*)Apk;
        const uint4* Al4 = Ah4 + KC*512;
        uint4* lds4 = (uint4*)smem;
        // prologue: stage chunk 0 -> par 0
        lds4[      tid*2  ] = Ah4[tid*2];   lds4[      tid*2+1] = Ah4[tid*2+1];
        lds4[512 + tid*2  ] = Al4[tid*2];   lds4[512 + tid*2+1] = Al4[tid*2+1];
        __syncthreads();
        int par = 0;
        for (int c=0; c<KC; ++c){
            uint4 pa0, pa1, pb0, pb1;
            if (c+1 < KC){   // prefetch next A chunk to regs (T14: issue early, LDS-write late)
                pa0 = Ah4[(c+1)*512 + tid*2]; pa1 = Ah4[(c+1)*512 + tid*2 + 1];
                pb0 = Al4[(c+1)*512 + tid*2]; pb1 = Al4[(c+1)*512 + tid*2 + 1];
            }
            const int tap = c>>2, icb = c&3;
            bf16x8 bh[2], bl[2];
            #pragma unroll
            for (int nt=0; nt<2; ++nt){
                size_t off = (size_t)pxo[nt][tap]*128 + icb*32 + l4*8;
                bh[nt] = as_bf(*(const uint4*)(Bh + off));
                bl[nt] = as_bf(*(const uint4*)(Bl + off));
            }
            const int pb = par*1024;
            #pragma unroll
            for (int mt=0; mt<8; ++mt){
                bf16x8 ah = as_bf(lds4[pb +       l4*128 + mt*16 + l15]);
                bf16x8 al = as_bf(lds4[pb + 512 + l4*128 + mt*16 + l15]);
                #pragma unroll
                for (int nt=0; nt<2; ++nt){
                    acc[mt][nt] = __builtin_amdgcn_mfma_f32_16x16x32_bf16(ah, bh[nt], acc[mt][nt], 0,0,0);
                    acc[mt][nt] = __builtin_amdgcn_mfma_f32_16x16x32_bf16(ah, bl[nt], acc[mt][nt], 0,0,0);
                    acc[mt][nt] = __builtin_amdgcn_mfma_f32_16x16x32_bf16(al, bh[nt], acc[mt][nt], 0,0,0);
                }
            }
            if (c+1 < KC){
                int np = (par^1)*1024;
                lds4[np +       tid*2] = pa0; lds4[np +       tid*2+1] = pa1;
                lds4[np + 512 + tid*2] = pb0; lds4[np + 512 + tid*2+1] = pb1;
            }
            __syncthreads();
            par ^= 1;
        }
    }

    if constexpr (MODE==0){
        #pragma unroll
        for (int mt=0; mt<4; ++mt)
            #pragma unroll
            for (int nt=0; nt<2; ++nt){
                int px = wpx0 + nt*16 + l15;
                #pragma unroll
                for (int r=0; r<4; ++r){
                    int oc = mt*16 + l4*4 + r;
                    float2 p = pre_t[(size_t)oc*SP + px];
                    p.x += acc[mt][nt][r];
                    p.y += acc[mt+4][nt][r];
                    pre_t[(size_t)oc*SP + px] = p;
                }
            }
    } else {
        const int wp = s&1;
        u16* Ch = H + (size_t)(dir*2+wp)*2*SPH;
        u16* Cl = Ch + SPH;
        const bool first = (s<=5);
        const u32 base = w*4096;
        #pragma unroll
        for (int mt=0; mt<4; ++mt)
            #pragma unroll
            for (int nt=0; nt<2; ++nt){
                int px = wpx0 + nt*16 + l15;
                int pxl = nt*16 + l15;
                #pragma unroll
                for (int r=0; r<4; ++r){
                    int oc = mt*16 + l4*4 + r;
                    float2 p = pre_t[(size_t)oc*SP + px];
                    float zr = p.x + acc[mt][nt][r];
                    float zi = p.y + acc[mt+4][nt][r];
                    float mag = sqrtf(zr*zr + zi*zi);
                    float sc = fmaxf(mag + modb[oc], 0.f) / (mag + 1e-8f);
                    float hr = sc*zr, him = sc*zi;
                    size_t oidx = ((size_t)oc*NT + t)*SP + px;
                    if (first) out[oidx] = make_float2(hr, him);
                    else { float2 o = out[oidx]; out[oidx] = make_float2(o.x+hr, o.y+him); }
                    u16 rh = bf16_rn(hr), ih = bf16_rn(him);
                    u16 rl = bf16_rn(hr - bf16_f(rh)), il = bf16_rn(him - bf16_f(ih));
                    int dwc = oc ^ (pxl&31);
                    smem[base +        pxl*64 + dwc] = (u32)rh | ((u32)ih<<16);
                    smem[base + 2048 + pxl*64 + dwc] = (u32)rl | ((u32)il<<16);
                }
            }
        // per-wave private region: readback (compiler orders LDS ops by aliasing)
        uint4* gh = (uint4*)Ch; uint4* gl = (uint4*)Cl;
        #pragma unroll
        for (int i=0; i<8; ++i){
            int pxr = i*4 + l4;
            int q = l15;
            uint4 v, v2;
            #pragma unroll
            for (int d=0; d<4; ++d){
                ((u32*)&v )[d] = smem[base +        pxr*64 + ((q*4+d) ^ (pxr&31))];
                ((u32*)&v2)[d] = smem[base + 2048 + pxr*64 + ((q*4+d) ^ (pxr&31))];
            }
            gh[(size_t)(wpx0+pxr)*16 + q] = v;
            gl[(size_t)(wpx0+pxr)*16 + q] = v2;
        }
    }
}

extern "C" void kernel_launch(void* const* d_in, const int* in_sizes, int n_in,
                              void* d_out, int out_size, void* d_ws, size_t ws_size,
                              hipStream_t stream)
{
    const float* in_r  = (const float*)d_in[0];
    const float* in_i  = (const float*)d_in[1];
    const float* it_r  = (const float*)d_in[2];
    const float* it_i  = (const float*)d_in[3];
    const float* w2_r  = (const float*)d_in[4];
    const float* w2_i  = (const float*)d_in[5];
    const float* b2_r  = (const float*)d_in[6];
    const float* b2_i  = (const float*)d_in[7];
    const float* whh_r = (const float*)d_in[8];
    const float* whh_i = (const float*)d_in[9];
    const float* bhh_r = (const float*)d_in[10];
    const float* bhh_i = (const float*)d_in[11];
    const float* wih_r = (const float*)d_in[12];
    const float* wih_i = (const float*)d_in[13];
    const float* bih_r = (const float*)d_in[14];
    const float* bih_i = (const float*)d_in[15];
    const float* mod_b = (const float*)d_in[16];

    char* ws = (char*)d_ws;
    float2* pre = (float2*)ws;                                   // 157,286,400 B
    u16*    H   = (u16*)(ws + 157286400);                        //  52,428,800 B
    u16*    Ahh = (u16*)(ws + 157286400 + 52428800);             //     589,824 B
    u16*    Aih = H + 4*SPH;                                     // overlaps dir1 h (dead until s=0)
    float2* out = (float2*)d_out;

    pack_w_kernel<<<KC, 128, 0, stream>>>(whh_r, whh_i, Ahh);
    pack_w_kernel<<<KC, 128, 0, stream>>>(wih_r, wih_i, Aih);
    i2h_kernel<<<dim3(100,8,12), 256, 0, stream>>>(in_r, in_i, w2_r, w2_i,
        b2_r, b2_i, bih_r, bih_i, bhh_r, bhh_i, pre);
    for (int t0=0; t0<NT; t0+=2){
        pack_iter_kernel<<<dim3(200,2), 256, 0, stream>>>(it_r, it_i, H, t0);
        gemm_kernel<0><<<dim3(200,2), 256, 0, stream>>>(Aih, H, pre + (size_t)t0*64*SP,
            nullptr, nullptr, nullptr, 0);
    }
    for (int s=0; s<NT; ++s)
        gemm_kernel<1><<<dim3(200,2), 256, 0, stream>>>(Ahh, nullptr, pre,
            out, mod_b, H, s);
}